// Round 7
// baseline (149.616 us; speedup 1.0000x reference)
//
#include <hip/hip_runtime.h>

#define NPTS 1000000
#define FDIM 64
#define CNUM 128
#define PSTRIDE 8320          // 8192 sums (c-major [c*64+f]) + 128 counts
#define NB1 1280              // k1 grid: 5 blocks/CU
#define NB3 1024              // k3 grid: 4 blocks/CU

typedef _Float16 half8 __attribute__((ext_vector_type(8)));
typedef float f32x4 __attribute__((ext_vector_type(4)));

// ---------------- K1: cluster sums via MFMA (onehot^T x X), f-quarter split -------
// One tile stream per block; wave w owns features [16w, 16w+16). acc[8] = 32 VGPR.
// Tile: M=16 clusters x N=16 feats x K=32 points; 8 ct MFMA per wave per tile.
// A/B layout: lane&15 = m/n; k = (lane>>4)*8 + i. C/D: col=lane&15, row=(lane>>4)*4+reg.
// Registers fund a 1-deep tile prefetch (T14). No LDS merge: waves disjoint in f.
__global__ __launch_bounds__(256, 5) void k1_partials(
    const float* __restrict__ feats, const int* __restrict__ labels,
    float* __restrict__ partials, int nblocks)
{
    __shared__ float cnt[CNUM];
    const int tid = threadIdx.x;
    if (tid < CNUM) cnt[tid] = 0.f;
    __syncthreads();

    const int lane = tid & 63;
    const int n15 = lane & 15;
    const int kb = (lane >> 4) * 8;        // k-slot base
    const int rowb = (lane >> 4) * 4;      // C/D row base
    const int fq = tid >> 6;               // feature quarter
    const int fbase = fq * 16;

    f32x4 acc[8];
    #pragma unroll
    for (int ct = 0; ct < 8; ++ct) acc[ct] = (f32x4){0.f, 0.f, 0.f, 0.f};

    const int ntiles = NPTS / 32;          // 31250
    int t = blockIdx.x;
    float fv[8]; int vl[8]; int cl = 0;
    if (t < ntiles) {
        const int p0 = t * 32;
        const float* fp = feats + (size_t)(p0 + kb) * FDIM + fbase + n15;
        const int* lp = labels + 2 * (p0 + kb) + 1;
        #pragma unroll
        for (int i = 0; i < 8; ++i) fv[i] = fp[i * FDIM];
        #pragma unroll
        for (int i = 0; i < 8; ++i) vl[i] = lp[2 * i];
        if (lane < 32) cl = labels[2 * (p0 + lane) + 1];
    }
    while (t < ntiles) {
        const int tn = t + nblocks;
        float fv2[8]; int vl2[8]; int cl2 = 0;
        if (tn < ntiles) {
            const int p0 = tn * 32;
            const float* fp = feats + (size_t)(p0 + kb) * FDIM + fbase + n15;
            const int* lp = labels + 2 * (p0 + kb) + 1;
            #pragma unroll
            for (int i = 0; i < 8; ++i) fv2[i] = fp[i * FDIM];
            #pragma unroll
            for (int i = 0; i < 8; ++i) vl2[i] = lp[2 * i];
            if (lane < 32) cl2 = labels[2 * (p0 + lane) + 1];
        }
        // counts: wave 0 only, one lane-op per point
        if (fq == 0 && lane < 32) atomicAdd(&cnt[cl], 1.0f);

        half8 B;
        #pragma unroll
        for (int i = 0; i < 8; ++i) B[i] = (_Float16)fv[i];
        #pragma unroll
        for (int ct = 0; ct < 8; ++ct) {
            const int cmine = ct * 16 + n15;
            union { unsigned u[4]; half8 h; } ua;
            #pragma unroll
            for (int j = 0; j < 4; ++j)
                ua.u[j] = ((vl[2 * j] == cmine) ? 0x3C00u : 0u)
                        | ((vl[2 * j + 1] == cmine) ? 0x3C000000u : 0u);
            acc[ct] = __builtin_amdgcn_mfma_f32_16x16x32_f16(ua.h, B, acc[ct], 0, 0, 0);
        }
        t = tn;
        #pragma unroll
        for (int i = 0; i < 8; ++i) { fv[i] = fv2[i]; vl[i] = vl2[i]; }
        cl = cl2;
    }
    __syncthreads();

    // direct register -> global writeout, c-major [c*64+f]
    float* dst = partials + (size_t)blockIdx.x * PSTRIDE;
    #pragma unroll
    for (int ct = 0; ct < 8; ++ct)
        #pragma unroll
        for (int reg = 0; reg < 4; ++reg) {
            const int c = ct * 16 + rowb + reg;
            dst[c * FDIM + fbase + n15] = acc[ct][reg];
        }
    if (tid < CNUM) dst[8192 + tid] = cnt[tid];
}

// ---------------- K2: reduce partials -> red (direct write) + zero tails --------
// red[0..8191] c-major [c*64+f]; red[8192..8319] counts. 520 blocks x 16 cols.
__global__ __launch_bounds__(256) void k2_reduce(
    const float* __restrict__ partials, int nblocks, float* __restrict__ red,
    float* __restrict__ ppsum, float* __restrict__ dsum, int* __restrict__ counter)
{
    const int tid = threadIdx.x;
    const int tsub = tid & 15, grp = tid >> 4;      // 16 groups of 16
    const int t0 = blockIdx.x * 16;                 // 520 blocks cover 8320
    float s = 0.f;
    #pragma unroll 8
    for (int b = grp; b < nblocks; b += 16)
        s += partials[(size_t)b * PSTRIDE + t0 + tsub];
    __shared__ float lred[16][17];
    lred[grp][tsub] = s;
    __syncthreads();
    if (tid < 16) {
        float tot = 0.f;
        #pragma unroll
        for (int q = 0; q < 16; ++q) tot += lred[q][tid];
        red[t0 + tid] = tot;                        // already c-major
    }
    if (blockIdx.x == 0) {
        if (tid >= 128) ppsum[tid - 128] = 0.f;
        if (tid == 64) dsum[0] = 0.f;
        if (tid == 65) counter[0] = 0;
    }
}

// ---------------- K3: variance term (prefetch depth 4) ----------------
__global__ __launch_bounds__(256, 4) void k3_var(
    const float4* __restrict__ feats4, const int* __restrict__ labels,
    const float* __restrict__ red, float* __restrict__ ppsum, int nblocks)
{
    __shared__ float4 mu4[CNUM * 16];   // [c][16] (quarter-wave shares c: no pad)
    __shared__ float lpp[CNUM];
    const int tid = threadIdx.x;
    for (int i = tid; i < 2048; i += 256) {
        float4 sv = ((const float4*)red)[i];
        float ci = 1.0f / red[8192 + (i >> 4)];
        mu4[i] = make_float4(sv.x * ci, sv.y * ci, sv.z * ci, sv.w * ci);
    }
    if (tid < CNUM) lpp[tid] = 0.f;
    __syncthreads();

    const int lane = tid & 63;
    const int k = lane & 15, g = lane >> 4;
    const int nwaves = nblocks * 4;
    const int wid = ((blockIdx.x << 8) + tid) >> 6;
    const int ntiles = NPTS / 16;           // 62500 tiles of 16 points

    int b = wid;
    float4 v[4]; int cc = 0;
    if (b < ntiles) {
        const float4* fp = feats4 + (size_t)b * 256 + lane;
        #pragma unroll
        for (int s = 0; s < 4; ++s) v[s] = fp[s * 64];
        cc = labels[2 * (b * 16 + k) + 1];
    }
    while (b < ntiles) {
        const int bn = b + nwaves;
        float4 vn[4]; int ccn = 0;
        if (bn < ntiles) {
            const float4* fp = feats4 + (size_t)bn * 256 + lane;
            #pragma unroll
            for (int s = 0; s < 4; ++s) vn[s] = fp[s * 64];
            ccn = labels[2 * (bn * 16 + k) + 1];
        }
        #pragma unroll
        for (int s = 0; s < 4; ++s) {
            const int c = __shfl(cc, 4 * s + g);
            float4 m = mu4[c * 16 + k];
            float dx = v[s].x - m.x, dy = v[s].y - m.y,
                  dz = v[s].z - m.z, dw = v[s].w - m.w;
            float sq = dx * dx + dy * dy + dz * dz + dw * dw;
            sq += __shfl_xor(sq, 1); sq += __shfl_xor(sq, 2);
            sq += __shfl_xor(sq, 4); sq += __shfl_xor(sq, 8);
            if (k == 0) {
                const float t = sqrtf(sq) - 0.5f;      // DELTA_VAR
                if (t > 0.f) atomicAdd(&lpp[c], t * t);
            }
        }
        b = bn;
        #pragma unroll
        for (int s = 0; s < 4; ++s) v[s] = vn[s];
        cc = ccn;
    }
    __syncthreads();
    if (tid < CNUM) atomicAdd(&ppsum[tid], lpp[tid]);
}

// ---------------- K45: pairwise dist loss + last-block finalize ----------------
__global__ __launch_bounds__(128) void k45_dist_final(
    const float* __restrict__ red, const float* __restrict__ ppsum,
    float* __restrict__ dsum, int* __restrict__ counter, float* __restrict__ out)
{
    __shared__ float4 mu4[CNUM * 17];   // padded: lanes read different rows
    __shared__ int lastflag;
    __shared__ float sv[2];
    const int tid = threadIdx.x;
    for (int i = tid; i < 2048; i += 128) {
        float4 s4 = ((const float4*)red)[i];
        float ci = 1.0f / red[8192 + (i >> 4)];
        mu4[(i >> 4) * 17 + (i & 15)] =
            make_float4(s4.x * ci, s4.y * ci, s4.z * ci, s4.w * ci);
    }
    __syncthreads();
    const int i = blockIdx.x, j = tid;
    float sq = 0.f;
    #pragma unroll
    for (int q = 0; q < 16; ++q) {
        float4 a = mu4[i * 17 + q], b = mu4[j * 17 + q];
        float dx = a.x - b.x, dy = a.y - b.y, dz = a.z - b.z, dw = a.w - b.w;
        sq += dx * dx + dy * dy + dz * dz + dw * dw;
    }
    float dl = 0.f;
    if (j != i) {
        const float r = 3.0f - sqrtf(sq);   // DELTA_DIST
        if (r > 0.f) dl = r * r;
    }
    #pragma unroll
    for (int m = 1; m < 64; m <<= 1) dl += __shfl_xor(dl, m);
    if ((tid & 63) == 0) atomicAdd(dsum, dl);
    __threadfence();
    __syncthreads();
    if (tid == 0) lastflag = (atomicAdd(counter, 1) == (int)gridDim.x - 1);
    __syncthreads();
    if (lastflag) {
        float v = ppsum[tid] / red[8192 + tid];
        #pragma unroll
        for (int m = 1; m < 64; m <<= 1) v += __shfl_xor(v, m);
        if ((tid & 63) == 0) sv[tid >> 6] = v;
    }
    __syncthreads();
    if (lastflag && tid == 0) {
        const float dtot = atomicAdd(dsum, 0.0f);   // device-scope read
        out[0] = (sv[0] + sv[1]) / (float)CNUM
               + dtot / (float)(CNUM * (CNUM - 1));
    }
}

extern "C" void kernel_launch(void* const* d_in, const int* in_sizes, int n_in,
                              void* d_out, int out_size, void* d_ws, size_t ws_size,
                              hipStream_t stream) {
    (void)in_sizes; (void)n_in; (void)out_size;
    const float* feats   = (const float*)d_in[0];
    const float4* feats4 = (const float4*)d_in[0];
    const int* labels    = (const int*)d_in[1];
    float* ws            = (float*)d_ws;
    float* out           = (float*)d_out;

    int nb1 = NB1;
    {
        size_t avail = ws_size / sizeof(float);
        size_t fixed = PSTRIDE + 128 + 2;           // red + ppsum + dsum + counter
        if (avail > fixed) {
            size_t cap = (avail - fixed) / PSTRIDE;
            if ((size_t)nb1 > cap) nb1 = (int)cap;
        } else nb1 = 1;
        if (nb1 < 1) nb1 = 1;
    }
    float* partials = ws;
    float* red      = ws + (size_t)nb1 * PSTRIDE;   // 16B-aligned
    float* ppsum    = red + PSTRIDE;
    float* dsum     = ppsum + 128;
    int*   counter  = (int*)(dsum + 1);

    k1_partials<<<nb1, 256, 0, stream>>>(feats, labels, partials, nb1);
    k2_reduce<<<PSTRIDE / 16, 256, 0, stream>>>(partials, nb1, red, ppsum, dsum, counter);
    k3_var<<<NB3, 256, 0, stream>>>(feats4, labels, red, ppsum, NB3);
    k45_dist_final<<<CNUM, 128, 0, stream>>>(red, ppsum, dsum, counter, out);
}